// Round 7
// baseline (5227.283 us; speedup 1.0000x reference)
//
#include <hip/hip_runtime.h>
#include <cstdint>
#include <cstddef>
#include <math.h>

#define NROWS 65536
#define DIM   512
#define KCB   256
#define RPW   8     // rows per wave
#define RPB   32    // rows per block (4 waves x 8 rows)
#define THR   256   // threads per block
#define LGS   260   // shared-buffer row stride in floats (16B-aligned, bank-spread)

// ---------------- Threefry-2x32 (jax partitionable; confirmed by R1 bulk match) ----------------
__host__ __device__ __forceinline__ uint32_t tf_rotl(uint32_t x, uint32_t r) {
  return (x << r) | (x >> (32u - r));
}
__host__ __device__ inline void tf2x32(uint32_t k0, uint32_t k1,
                                       uint32_t x0, uint32_t x1,
                                       uint32_t& o0, uint32_t& o1) {
  uint32_t k2 = k0 ^ k1 ^ 0x1BD11BDAu;
  x0 += k0; x1 += k1;
#define TF_R(r) { x0 += x1; x1 = tf_rotl(x1, r); x1 ^= x0; }
  TF_R(13) TF_R(15) TF_R(26) TF_R(6)
  x0 += k1; x1 += k2 + 1u;
  TF_R(17) TF_R(29) TF_R(16) TF_R(24)
  x0 += k2; x1 += k0 + 2u;
  TF_R(13) TF_R(15) TF_R(26) TF_R(6)
  x0 += k0; x1 += k1 + 3u;
  TF_R(17) TF_R(29) TF_R(16) TF_R(24)
  x0 += k1; x1 += k2 + 4u;
  TF_R(13) TF_R(15) TF_R(26) TF_R(6)
  x0 += k2; x1 += k0 + 5u;
#undef TF_R
  o0 = x0; o1 = x1;
}

// f32 gumbel, replicating np-f32: u from jax bits, then -log32(-log32(u)),
// each f32 log obtained by correctly-rounding the f64 log.
__device__ __forceinline__ float gumbel32(uint32_t k0, uint32_t k1, uint32_t j) {
  uint32_t o0, o1;
  tf2x32(k0, k1, 0u, j, o0, o1);
  uint32_t bits = o0 ^ o1;
  float f = __uint_as_float((bits >> 9) | 0x3f800000u) - 1.0f;
  if (f == 0.0f) f = 1.17549435e-38f;
  float t1 = (float)log((double)f);
  float t2 = (float)log((double)(-t1));
  return -t2;
}

__device__ __forceinline__ float exp32cr(float z) {
  return (float)exp((double)z);
}

// wave argmax: f32 value, smaller index wins ties (np first-occurrence)
__device__ __forceinline__ void argmax64(float& v, int& i) {
#pragma unroll
  for (int off = 32; off >= 1; off >>= 1) {
    float ov = __shfl_xor(v, off);
    int   oi = __shfl_xor(i, off);
    if (ov > v || (ov == v && oi < i)) { v = ov; i = oi; }
  }
}

// broadcast one lane's float to all lanes via SGPR (uniform lane index)
__device__ __forceinline__ float rdlane(float v, int lane) {
  return __int_as_float(__builtin_amdgcn_readlane(__float_as_int(v), lane));
}

// ---------------- cpd[i][d][k] = (C_i @ A_i)[k][d], seq-e FMA (BLAS order) ----------------
__global__ __launch_bounds__(256) void k_cproj(const float* __restrict__ C,
                                               const float* __restrict__ A,
                                               float* __restrict__ cpd) {
  const int i = blockIdx.x >> 6;
  const int d0 = (blockIdx.x & 63) * 8;
  const int t = threadIdx.x;          // t = k
  const float* Ai = A + (size_t)i * DIM * DIM;
  const float* Ci = C + (size_t)i * KCB * DIM;
  float acc[8] = {};
  for (int e = 0; e < DIM; ++e) {
    float cv = Ci[(size_t)t * DIM + e];
#pragma unroll
    for (int dd = 0; dd < 8; ++dd)
      acc[dd] = fmaf(cv, Ai[(size_t)e * DIM + d0 + dd], acc[dd]);
  }
#pragma unroll
  for (int dd = 0; dd < 8; ++dd)
    cpd[((size_t)i * DIM + d0 + dd) * KCB + t] = acc[dd];
}

// ---------------- Per-stage: LDS-broadcast GEMMs + rotating register prefetch ----------------
// R6 structure (uniform-ds_read broadcast of x/p, readlane broadcast of xp, 33KB LDS
// overlay) with one change: ph0b's A-stream and ph4's Wr-stream get a 1-pair-deep
// rotating register prefetch (issue iter i+1's 4 b128 before iter i's FMA block,
// epilogue peel) to hide L2 latency that showed as the 23% VALU stall. All arithmetic
// sequences byte-identical to R6 (verified): strict ascending K per output, mul/add
// split in ph1, verified ph2/ph2b bodies.
__global__ __launch_bounds__(THR, 4) void k_stage(
    const float* __restrict__ Xin,    // stage input x rows
    float* __restrict__ Xout,         // stage output x rows (stage<3); own-rows in-place safe
    const float* __restrict__ Ai,     // W_att[i] [512][512]
    const float* __restrict__ cpdi,   // cproj^T  [512 d][256 k]
    const float* __restrict__ Cbi,    // codebooks[i] [256][512]
    const float* __restrict__ Wr,     // W_rnn [512][512]
    float* __restrict__ out,
    uint32_t kh0, uint32_t kh1, uint32_t ks0, uint32_t ks1, int stage) {
  __shared__ __align__(16) float sh[RPB * LGS];   // x-half / logits+exp / p-half
  __shared__ int selL[RPB]; __shared__ int idxL[RPB]; __shared__ float wsL[RPB];
  const int t = threadIdx.x;
  const int L = t & 63;            // lane
  const int rb = (t >> 6) * RPW;   // wave's rows: rb..rb+7
  const int n0 = blockIdx.x * RPB;

  // ph0b: xp[n][d] = seq-e FMA of x[n][e]*A[e][d]; lane L owns d = L*8+c.
  // x staged in LDS halves; broadcast via uniform ds_read (same addr all lanes).
  float xp[RPW][8];
#pragma unroll
  for (int r = 0; r < RPW; ++r)
#pragma unroll
    for (int c = 0; c < 8; ++c) xp[r][c] = 0.0f;

#pragma unroll 1
  for (int h = 0; h < 2; ++h) {
    // stage x[:, h*256 .. h*256+256) for all 32 block rows (coalesced b128)
#pragma unroll
    for (int q = 0; q < 8; ++q) {
      const int idx = q * 256 + t;
      const int row = idx >> 6, c4 = idx & 63;
      *(float4*)&sh[row * LGS + c4 * 4] =
          *(const float4*)&Xin[(size_t)(n0 + row) * 512 + h * 256 + c4 * 4];
    }
    __syncthreads();
    const float* Ah = Ai + (size_t)(h * 256) * 512 + L * 8;
    // prologue: load e-pair 0
    float4 a00 = *(const float4*)(Ah);
    float4 a01 = *(const float4*)(Ah + 4);
    float4 a10 = *(const float4*)(Ah + 512);
    float4 a11 = *(const float4*)(Ah + 516);
#pragma unroll 1
    for (int eh = 0; eh + 2 < 256; eh += 2) {
      // prefetch next e-pair
      const float* An = Ah + (size_t)(eh + 2) * 512;
      float4 b00 = *(const float4*)(An);
      float4 b01 = *(const float4*)(An + 4);
      float4 b10 = *(const float4*)(An + 512);
      float4 b11 = *(const float4*)(An + 516);
      float2 xs[RPW];
#pragma unroll
      for (int r = 0; r < RPW; ++r)
        xs[r] = *(const float2*)&sh[(rb + r) * LGS + eh];   // uniform: broadcast
      {
        float av0[8] = {a00.x, a00.y, a00.z, a00.w, a01.x, a01.y, a01.z, a01.w};
        float av1[8] = {a10.x, a10.y, a10.z, a10.w, a11.x, a11.y, a11.z, a11.w};
#pragma unroll
        for (int r = 0; r < RPW; ++r) {
#pragma unroll
          for (int c = 0; c < 8; ++c) xp[r][c] = fmaf(xs[r].x, av0[c], xp[r][c]);
#pragma unroll
          for (int c = 0; c < 8; ++c) xp[r][c] = fmaf(xs[r].y, av1[c], xp[r][c]);
        }
      }
      a00 = b00; a01 = b01; a10 = b10; a11 = b11;
    }
    {  // epilogue: e-pair at eh = 254 (regs already loaded)
      const int eh = 254;
      float2 xs[RPW];
#pragma unroll
      for (int r = 0; r < RPW; ++r)
        xs[r] = *(const float2*)&sh[(rb + r) * LGS + eh];
      float av0[8] = {a00.x, a00.y, a00.z, a00.w, a01.x, a01.y, a01.z, a01.w};
      float av1[8] = {a10.x, a10.y, a10.z, a10.w, a11.x, a11.y, a11.z, a11.w};
#pragma unroll
      for (int r = 0; r < RPW; ++r) {
#pragma unroll
        for (int c = 0; c < 8; ++c) xp[r][c] = fmaf(xs[r].x, av0[c], xp[r][c]);
#pragma unroll
        for (int c = 0; c < 8; ++c) xp[r][c] = fmaf(xs[r].y, av1[c], xp[r][c]);
      }
    }
    __syncthreads();   // half consumed before overwrite / before lgss reuse
  }

  // ph1: logit[n][k] = seq-d (mul,add) of xp[n][d]*cpd[d][k]; lane L owns k = 4L+s.
  // One coalesced b128 of cpd row d per lane; xp broadcast from regs (lane db, reg j).
  float lacc[RPW][4];
#pragma unroll
  for (int r = 0; r < RPW; ++r)
#pragma unroll
    for (int s = 0; s < 4; ++s) lacc[r][s] = 0.0f;
  for (int db = 0; db < 64; ++db) {
#pragma unroll
    for (int j = 0; j < 8; ++j) {
      const int d = db * 8 + j;
      float4 cv = *(const float4*)(cpdi + (size_t)d * 256 + 4 * L);
      float xs[RPW];
#pragma unroll
      for (int r = 0; r < RPW; ++r) xs[r] = rdlane(xp[r][j], db);
#pragma unroll
      for (int r = 0; r < RPW; ++r) {
        lacc[r][0] = __fadd_rn(lacc[r][0], __fmul_rn(xs[r], cv.x));
        lacc[r][1] = __fadd_rn(lacc[r][1], __fmul_rn(xs[r], cv.y));
        lacc[r][2] = __fadd_rn(lacc[r][2], __fmul_rn(xs[r], cv.z));
        lacc[r][3] = __fadd_rn(lacc[r][3], __fmul_rn(xs[r], cv.w));
      }
    }
  }
  // stash logits at absolute k = 4L+s (float4 per row)
#pragma unroll
  for (int r = 0; r < RPW; ++r)
    *(float4*)&sh[(rb + r) * LGS + 4 * L] =
        make_float4(lacc[r][0], lacc[r][1], lacc[r][2], lacc[r][3]);
  __syncthreads();

  // ph2: per-row decisions (wave owns 8 rows; lane c owns k = sub*64+c).
  // exp values overwrite logits IN PLACE (same thread, same address — R3..R6-verified).
  {
    const int c = t & 63;
#pragma unroll 1
    for (int rr2 = 0; rr2 < RPW; ++rr2) {
      const int r = (t >> 6) * RPW + rr2;
      const int n = n0 + r;
      const uint32_t jb = (uint32_t)n * 256u;
      float l[4];
#pragma unroll
      for (int sub = 0; sub < 4; ++sub) l[sub] = sh[r * LGS + sub * 64 + c];
      // idx: first-max over f32 logits
      float bv = l[0]; int bi = c;
#pragma unroll
      for (int sub = 1; sub < 4; ++sub)
        if (l[sub] > bv) { bv = l[sub]; bi = sub * 64 + c; }
      argmax64(bv, bi);
      // hard sel: first-max over (l+g_hard)/0.9f
      float sv = 0.0f; int si = 0;
#pragma unroll
      for (int sub = 0; sub < 4; ++sub) {
        float g = gumbel32(kh0, kh1, jb + (uint32_t)(sub * 64 + c));
        float s = __fdiv_rn(__fadd_rn(l[sub], g), 0.9f);
        if (sub == 0 || s > sv) { sv = s; si = sub * 64 + c; }
      }
      argmax64(sv, si);
      // soft: scores, row max, exp (CR f32)
      float ssv[4];
#pragma unroll
      for (int sub = 0; sub < 4; ++sub) {
        float g = gumbel32(ks0, ks1, jb + (uint32_t)(sub * 64 + c));
        ssv[sub] = __fdiv_rn(__fadd_rn(l[sub], g), 0.9f);
      }
      float m = fmaxf(fmaxf(ssv[0], ssv[1]), fmaxf(ssv[2], ssv[3]));
#pragma unroll
      for (int off = 32; off >= 1; off >>= 1) m = fmaxf(m, __shfl_xor(m, off));
#pragma unroll
      for (int sub = 0; sub < 4; ++sub)
        sh[r * LGS + sub * 64 + c] = exp32cr(__fsub_rn(ssv[sub], m));
      if (c == 0) { selL[r] = si; idxL[r] = bi; }
    }
  }
  __syncthreads();

  // ph2b: numpy-pairwise softmax denom; 8 threads per row (32 rows).
  // Exact order: per half, acc_j = a[j]+a[8+j]+...+a[120+j] (15 seq adds), then
  // commutative-only shfl_xor(1,2,4) tree = ((r0+r1)+(r2+r3))+((r4+r5)+(r6+r7));
  // S = fadd(half0, half1) in ref order.  (R5/R6-verified)
  {
    const int r = t >> 3;        // 0..31
    const int j = t & 7;
    const float* a = sh + r * LGS;
    float acc0 = a[j];
#pragma unroll
    for (int i = 1; i < 16; ++i) acc0 = __fadd_rn(acc0, a[j + 8 * i]);
    float s0 = __fadd_rn(acc0, __shfl_xor(acc0, 1));
    s0 = __fadd_rn(s0, __shfl_xor(s0, 2));
    s0 = __fadd_rn(s0, __shfl_xor(s0, 4));
    float acc1 = a[128 + j];
#pragma unroll
    for (int i = 1; i < 16; ++i) acc1 = __fadd_rn(acc1, a[128 + j + 8 * i]);
    float s1 = __fadd_rn(acc1, __shfl_xor(acc1, 1));
    s1 = __fadd_rn(s1, __shfl_xor(s1, 2));
    s1 = __fadd_rn(s1, __shfl_xor(s1, 4));
    float S = __fadd_rn(s0, s1);
    if (j == 0) {
      const int n = n0 + r;
      int sel = selL[r];
      float wsv = __fdiv_rn(sh[r * LGS + sel], S);
      wsL[r] = __fadd_rn(__fsub_rn(1.0f, wsv), wsv);
      out[(size_t)NROWS * DIM + (size_t)n * 4 + stage] = (float)idxL[r];
    }
  }
  __syncthreads();

  // ph3/ph4 in column halves: p = fl32(wstar * C[sel][col]) (4 cols/lane/half),
  // out_sum RMW (per-col, ref order), p-half staged in sh (overlays dead exp buf),
  // ph4 broadcasts p via uniform ds_read; a2 accumulates d = 0..511 ascending.
  // ph4's Wr-stream gets the same rotating 1-pair-deep prefetch as ph0b's A-stream.
  float a2[RPW][8];
  if (stage < 3) {
#pragma unroll
    for (int r = 0; r < RPW; ++r)
#pragma unroll
      for (int c = 0; c < 8; ++c) a2[r][c] = 0.0f;
  }
#pragma unroll 1
  for (int h = 0; h < 2; ++h) {
    float4 p4[RPW];
#pragma unroll
    for (int r = 0; r < RPW; ++r) {
      const int n = n0 + rb + r;
      const int sel = selL[rb + r];
      const float wv = wsL[rb + r];
      float4 cv = *(const float4*)(Cbi + (size_t)sel * 512 + h * 256 + 4 * L);
      p4[r].x = __fmul_rn(wv, cv.x); p4[r].y = __fmul_rn(wv, cv.y);
      p4[r].z = __fmul_rn(wv, cv.z); p4[r].w = __fmul_rn(wv, cv.w);
      float* orow = out + (size_t)n * 512 + h * 256 + 4 * L;
      if (stage == 0) {
        *(float4*)orow = p4[r];
      } else {
        float4 o = *(const float4*)orow;
        o.x = __fadd_rn(o.x, p4[r].x); o.y = __fadd_rn(o.y, p4[r].y);
        o.z = __fadd_rn(o.z, p4[r].z); o.w = __fadd_rn(o.w, p4[r].w);
        *(float4*)orow = o;
      }
    }
    if (stage < 3) {
      __syncthreads();   // exp buf (h=0) / prev p-half (h=1) fully consumed
#pragma unroll
      for (int r = 0; r < RPW; ++r)
        *(float4*)&sh[(rb + r) * LGS + 4 * L] = p4[r];
      __syncthreads();
      const float* Wh = Wr + (size_t)(h * 256) * 512 + L * 8;
      // prologue: load d-pair 0
      float4 w00 = *(const float4*)(Wh);
      float4 w01 = *(const float4*)(Wh + 4);
      float4 w10 = *(const float4*)(Wh + 512);
      float4 w11 = *(const float4*)(Wh + 516);
#pragma unroll 1
      for (int dl = 0; dl + 2 < 256; dl += 2) {
        // prefetch next d-pair
        const float* Wn = Wh + (size_t)(dl + 2) * 512;
        float4 v00 = *(const float4*)(Wn);
        float4 v01 = *(const float4*)(Wn + 4);
        float4 v10 = *(const float4*)(Wn + 512);
        float4 v11 = *(const float4*)(Wn + 516);
        float2 ps[RPW];
#pragma unroll
        for (int r = 0; r < RPW; ++r)
          ps[r] = *(const float2*)&sh[(rb + r) * LGS + dl];   // uniform: broadcast
        {
          float wv0[8] = {w00.x, w00.y, w00.z, w00.w, w01.x, w01.y, w01.z, w01.w};
          float wv1[8] = {w10.x, w10.y, w10.z, w10.w, w11.x, w11.y, w11.z, w11.w};
#pragma unroll
          for (int r = 0; r < RPW; ++r) {
#pragma unroll
            for (int c = 0; c < 8; ++c) a2[r][c] = fmaf(ps[r].x, wv0[c], a2[r][c]);
#pragma unroll
            for (int c = 0; c < 8; ++c) a2[r][c] = fmaf(ps[r].y, wv1[c], a2[r][c]);
          }
        }
        w00 = v00; w01 = v01; w10 = v10; w11 = v11;
      }
      {  // epilogue: d-pair at dl = 254 (regs already loaded)
        const int dl = 254;
        float2 ps[RPW];
#pragma unroll
        for (int r = 0; r < RPW; ++r)
          ps[r] = *(const float2*)&sh[(rb + r) * LGS + dl];
        float wv0[8] = {w00.x, w00.y, w00.z, w00.w, w01.x, w01.y, w01.z, w01.w};
        float wv1[8] = {w10.x, w10.y, w10.z, w10.w, w11.x, w11.y, w11.z, w11.w};
#pragma unroll
        for (int r = 0; r < RPW; ++r) {
#pragma unroll
          for (int c = 0; c < 8; ++c) a2[r][c] = fmaf(ps[r].x, wv0[c], a2[r][c]);
#pragma unroll
          for (int c = 0; c < 8; ++c) a2[r][c] = fmaf(ps[r].y, wv1[c], a2[r][c]);
        }
      }
    }
  }

  // x_next = x - p@Wr, write to global (own rows; in-place safe)
  if (stage < 3) {
#pragma unroll
    for (int r = 0; r < RPW; ++r) {
      const float* px = Xin + (size_t)(n0 + rb + r) * 512 + L * 8;
      float4 x0 = *(const float4*)px;
      float4 x1 = *(const float4*)(px + 4);
      float4 o0, o1;
      o0.x = __fsub_rn(x0.x, a2[r][0]); o0.y = __fsub_rn(x0.y, a2[r][1]);
      o0.z = __fsub_rn(x0.z, a2[r][2]); o0.w = __fsub_rn(x0.w, a2[r][3]);
      o1.x = __fsub_rn(x1.x, a2[r][4]); o1.y = __fsub_rn(x1.y, a2[r][5]);
      o1.z = __fsub_rn(x1.z, a2[r][6]); o1.w = __fsub_rn(x1.w, a2[r][7]);
      float* pxo = Xout + (size_t)(n0 + rb + r) * 512 + L * 8;
      *(float4*)pxo = o0;
      *(float4*)(pxo + 4) = o1;
    }
  }
}

extern "C" void kernel_launch(void* const* d_in, const int* in_sizes, int n_in,
                              void* d_out, int out_size, void* d_ws, size_t ws_size,
                              hipStream_t stream) {
  const float* x  = (const float*)d_in[0];   // [65536,512]
  const float* Cb = (const float*)d_in[1];   // [4,256,512]
  const float* A  = (const float*)d_in[2];   // [4,512,512]
  const float* Wr = (const float*)d_in[3];   // [512,512]
  float* out = (float*)d_out;
  float* ws  = (float*)d_ws;

  float* cpd  = ws;                          // 4*512*256 = 524288 f (2 MB)
  float* xcur = ws + 524288;                 // 65536*512 f (134 MB)

  // keys: fold_in(key(42), i) -> split -> (k_soft = keys[0], k_hard = keys[1])
  uint32_t kh[4][2], ks[4][2];
  for (uint32_t i = 0; i < 4; ++i) {
    uint32_t f0, f1, a0, a1, b0, b1;
    tf2x32(0u, 42u, 0u, i, f0, f1);
    tf2x32(f0, f1, 0u, 0u, a0, a1);   // keys[0] -> k_soft
    tf2x32(f0, f1, 0u, 1u, b0, b1);   // keys[1] -> k_hard
    ks[i][0] = a0; ks[i][1] = a1;
    kh[i][0] = b0; kh[i][1] = b1;
  }

  k_cproj<<<dim3(256), dim3(256), 0, stream>>>(Cb, A, cpd);

  const int NB = NROWS / RPB;  // 2048
  for (int i = 0; i < 4; ++i) {
    const float* Xi = (i == 0) ? x : xcur;
    k_stage<<<dim3(NB), dim3(THR), 0, stream>>>(
        Xi, xcur, A + (size_t)i * DIM * DIM, cpd + (size_t)i * DIM * KCB,
        Cb + (size_t)i * KCB * DIM, Wr, out,
        kh[i][0], kh[i][1], ks[i][0], ks[i][1], i);
  }
}

// Round 8
// 4997.269 us; speedup vs baseline: 1.0460x; 1.0460x over previous
//
#include <hip/hip_runtime.h>
#include <cstdint>
#include <cstddef>
#include <math.h>

#define NROWS 65536
#define DIM   512
#define KCB   256
#define RPW   8     // rows per wave
#define RPB   32    // rows per block (4 waves x 8 rows)
#define THR   256   // threads per block
#define LGS   260   // shared-buffer row stride in floats (16B-aligned, bank-spread)

// ---------------- Threefry-2x32 (jax partitionable; confirmed by R1 bulk match) ----------------
__host__ __device__ __forceinline__ uint32_t tf_rotl(uint32_t x, uint32_t r) {
  return (x << r) | (x >> (32u - r));
}
__host__ __device__ inline void tf2x32(uint32_t k0, uint32_t k1,
                                       uint32_t x0, uint32_t x1,
                                       uint32_t& o0, uint32_t& o1) {
  uint32_t k2 = k0 ^ k1 ^ 0x1BD11BDAu;
  x0 += k0; x1 += k1;
#define TF_R(r) { x0 += x1; x1 = tf_rotl(x1, r); x1 ^= x0; }
  TF_R(13) TF_R(15) TF_R(26) TF_R(6)
  x0 += k1; x1 += k2 + 1u;
  TF_R(17) TF_R(29) TF_R(16) TF_R(24)
  x0 += k2; x1 += k0 + 2u;
  TF_R(13) TF_R(15) TF_R(26) TF_R(6)
  x0 += k0; x1 += k1 + 3u;
  TF_R(17) TF_R(29) TF_R(16) TF_R(24)
  x0 += k1; x1 += k2 + 4u;
  TF_R(13) TF_R(15) TF_R(26) TF_R(6)
  x0 += k2; x1 += k0 + 5u;
#undef TF_R
  o0 = x0; o1 = x1;
}

// f32 gumbel, replicating np-f32: u from jax bits, then -log32(-log32(u)),
// each f32 log obtained by correctly-rounding the f64 log.
__device__ __forceinline__ float gumbel32(uint32_t k0, uint32_t k1, uint32_t j) {
  uint32_t o0, o1;
  tf2x32(k0, k1, 0u, j, o0, o1);
  uint32_t bits = o0 ^ o1;
  float f = __uint_as_float((bits >> 9) | 0x3f800000u) - 1.0f;
  if (f == 0.0f) f = 1.17549435e-38f;
  float t1 = (float)log((double)f);
  float t2 = (float)log((double)(-t1));
  return -t2;
}

__device__ __forceinline__ float exp32cr(float z) {
  return (float)exp((double)z);
}

// wave argmax: f32 value, smaller index wins ties (np first-occurrence)
__device__ __forceinline__ void argmax64(float& v, int& i) {
#pragma unroll
  for (int off = 32; off >= 1; off >>= 1) {
    float ov = __shfl_xor(v, off);
    int   oi = __shfl_xor(i, off);
    if (ov > v || (ov == v && oi < i)) { v = ov; i = oi; }
  }
}

// ---------------- cpd[i][d][k] = (C_i @ A_i)[k][d], seq-e FMA (BLAS order) ----------------
__global__ __launch_bounds__(256) void k_cproj(const float* __restrict__ C,
                                               const float* __restrict__ A,
                                               float* __restrict__ cpd) {
  const int i = blockIdx.x >> 6;
  const int d0 = (blockIdx.x & 63) * 8;
  const int t = threadIdx.x;          // t = k
  const float* Ai = A + (size_t)i * DIM * DIM;
  const float* Ci = C + (size_t)i * KCB * DIM;
  float acc[8] = {};
  for (int e = 0; e < DIM; ++e) {
    float cv = Ci[(size_t)t * DIM + e];
#pragma unroll
    for (int dd = 0; dd < 8; ++dd)
      acc[dd] = fmaf(cv, Ai[(size_t)e * DIM + d0 + dd], acc[dd]);
  }
#pragma unroll
  for (int dd = 0; dd < 8; ++dd)
    cpd[((size_t)i * DIM + d0 + dd) * KCB + t] = acc[dd];
}

// ---------------- Per-stage: LDS-broadcast everywhere (R6 + ph1 readlane->ds_read) ----------------
// R6 structure verbatim (uniform-ds_read broadcast of x/p in ph0b/ph4, 33KB LDS overlay,
// NO explicit prefetch — R7 showed it hurts), with ONE change: ph1's xp broadcast moves
// from v_readlane (VALU pipe, 4096 inst/wave) to the same uniform-ds_read mechanism
// (idle LDS pipe): xp is spilled to sh in d-halves (32 owning lanes per half) and
// broadcast-read per d-pair. xp registers die at ph1 entry -> scheduler headroom.
// All arithmetic sequences bit-identical: strict ascending d per (r,k), mul/add split,
// verified ph2/ph2b/ph3/ph4 bodies.
__global__ __launch_bounds__(THR, 4) void k_stage(
    const float* __restrict__ Xin,    // stage input x rows
    float* __restrict__ Xout,         // stage output x rows (stage<3); own-rows in-place safe
    const float* __restrict__ Ai,     // W_att[i] [512][512]
    const float* __restrict__ cpdi,   // cproj^T  [512 d][256 k]
    const float* __restrict__ Cbi,    // codebooks[i] [256][512]
    const float* __restrict__ Wr,     // W_rnn [512][512]
    float* __restrict__ out,
    uint32_t kh0, uint32_t kh1, uint32_t ks0, uint32_t ks1, int stage) {
  __shared__ __align__(16) float sh[RPB * LGS];   // x-half / xp-half / logits+exp / p-half
  __shared__ int selL[RPB]; __shared__ int idxL[RPB]; __shared__ float wsL[RPB];
  const int t = threadIdx.x;
  const int L = t & 63;            // lane
  const int rb = (t >> 6) * RPW;   // wave's rows: rb..rb+7
  const int n0 = blockIdx.x * RPB;

  // ph0b: xp[n][d] = seq-e FMA of x[n][e]*A[e][d]; lane L owns d = L*8+c.
  // x staged in LDS halves; broadcast via uniform ds_read (same addr all lanes).
  float xp[RPW][8];
#pragma unroll
  for (int r = 0; r < RPW; ++r)
#pragma unroll
    for (int c = 0; c < 8; ++c) xp[r][c] = 0.0f;

#pragma unroll 1
  for (int h = 0; h < 2; ++h) {
    // stage x[:, h*256 .. h*256+256) for all 32 block rows (coalesced b128)
#pragma unroll
    for (int q = 0; q < 8; ++q) {
      const int idx = q * 256 + t;
      const int row = idx >> 6, c4 = idx & 63;
      *(float4*)&sh[row * LGS + c4 * 4] =
          *(const float4*)&Xin[(size_t)(n0 + row) * 512 + h * 256 + c4 * 4];
    }
    __syncthreads();
    for (int eh = 0; eh < 256; eh += 2) {
      const int e = h * 256 + eh;
      const float* ar0 = Ai + (size_t)e * 512 + L * 8;
      float4 a00 = *(const float4*)ar0;
      float4 a01 = *(const float4*)(ar0 + 4);
      float4 a10 = *(const float4*)(ar0 + 512);
      float4 a11 = *(const float4*)(ar0 + 516);
      float av0[8] = {a00.x, a00.y, a00.z, a00.w, a01.x, a01.y, a01.z, a01.w};
      float av1[8] = {a10.x, a10.y, a10.z, a10.w, a11.x, a11.y, a11.z, a11.w};
      float2 xs[RPW];
#pragma unroll
      for (int r = 0; r < RPW; ++r)
        xs[r] = *(const float2*)&sh[(rb + r) * LGS + eh];   // uniform: broadcast
#pragma unroll
      for (int r = 0; r < RPW; ++r) {
#pragma unroll
        for (int c = 0; c < 8; ++c) xp[r][c] = fmaf(xs[r].x, av0[c], xp[r][c]);
#pragma unroll
        for (int c = 0; c < 8; ++c) xp[r][c] = fmaf(xs[r].y, av1[c], xp[r][c]);
      }
    }
    __syncthreads();   // half consumed before overwrite / before reuse
  }

  // ph1: logit[n][k] = seq-d (mul,add) of xp[n][d]*cpd[d][k]; lane L owns k = 4L+s.
  // xp spilled to sh in d-halves (lanes owning the half's d-range write 8 rows x 8 d),
  // then broadcast per d-pair via uniform ds_read — replaces 4096 v_readlane/wave.
  // Per (r,k): d strictly ascending 0..511 across halves; mul/add split (np.einsum order).
  float lacc[RPW][4];
#pragma unroll
  for (int r = 0; r < RPW; ++r)
#pragma unroll
    for (int s = 0; s < 4; ++s) lacc[r][s] = 0.0f;
#pragma unroll 1
  for (int h = 0; h < 2; ++h) {
    if (h) __syncthreads();            // h=0 covered by ph0b's trailing barrier
    {
      const int lh = L - h * 32;       // 0..31 if this lane's d-range is in half h
      if (lh >= 0 && lh < 32) {
#pragma unroll
        for (int r = 0; r < RPW; ++r) {
          *(float4*)&sh[(rb + r) * LGS + lh * 8] =
              make_float4(xp[r][0], xp[r][1], xp[r][2], xp[r][3]);
          *(float4*)&sh[(rb + r) * LGS + lh * 8 + 4] =
              make_float4(xp[r][4], xp[r][5], xp[r][6], xp[r][7]);
        }
      }
    }
    __syncthreads();
    for (int dl = 0; dl < 256; dl += 2) {
      const int d = h * 256 + dl;
      float4 cv0 = *(const float4*)(cpdi + (size_t)d * 256 + 4 * L);
      float4 cv1 = *(const float4*)(cpdi + (size_t)(d + 1) * 256 + 4 * L);
      float2 xs[RPW];
#pragma unroll
      for (int r = 0; r < RPW; ++r)
        xs[r] = *(const float2*)&sh[(rb + r) * LGS + dl];   // uniform: broadcast
#pragma unroll
      for (int r = 0; r < RPW; ++r) {
        lacc[r][0] = __fadd_rn(lacc[r][0], __fmul_rn(xs[r].x, cv0.x));
        lacc[r][1] = __fadd_rn(lacc[r][1], __fmul_rn(xs[r].x, cv0.y));
        lacc[r][2] = __fadd_rn(lacc[r][2], __fmul_rn(xs[r].x, cv0.z));
        lacc[r][3] = __fadd_rn(lacc[r][3], __fmul_rn(xs[r].x, cv0.w));
        lacc[r][0] = __fadd_rn(lacc[r][0], __fmul_rn(xs[r].y, cv1.x));
        lacc[r][1] = __fadd_rn(lacc[r][1], __fmul_rn(xs[r].y, cv1.y));
        lacc[r][2] = __fadd_rn(lacc[r][2], __fmul_rn(xs[r].y, cv1.z));
        lacc[r][3] = __fadd_rn(lacc[r][3], __fmul_rn(xs[r].y, cv1.w));
      }
    }
  }
  __syncthreads();   // all xp reads done before lg overwrites sh
  // stash logits at absolute k = 4L+s (float4 per row)
#pragma unroll
  for (int r = 0; r < RPW; ++r)
    *(float4*)&sh[(rb + r) * LGS + 4 * L] =
        make_float4(lacc[r][0], lacc[r][1], lacc[r][2], lacc[r][3]);
  __syncthreads();

  // ph2: per-row decisions (wave owns 8 rows; lane c owns k = sub*64+c).
  // exp values overwrite logits IN PLACE (same thread, same address — R3..R6-verified).
  {
    const int c = t & 63;
#pragma unroll 1
    for (int rr2 = 0; rr2 < RPW; ++rr2) {
      const int r = (t >> 6) * RPW + rr2;
      const int n = n0 + r;
      const uint32_t jb = (uint32_t)n * 256u;
      float l[4];
#pragma unroll
      for (int sub = 0; sub < 4; ++sub) l[sub] = sh[r * LGS + sub * 64 + c];
      // idx: first-max over f32 logits
      float bv = l[0]; int bi = c;
#pragma unroll
      for (int sub = 1; sub < 4; ++sub)
        if (l[sub] > bv) { bv = l[sub]; bi = sub * 64 + c; }
      argmax64(bv, bi);
      // hard sel: first-max over (l+g_hard)/0.9f
      float sv = 0.0f; int si = 0;
#pragma unroll
      for (int sub = 0; sub < 4; ++sub) {
        float g = gumbel32(kh0, kh1, jb + (uint32_t)(sub * 64 + c));
        float s = __fdiv_rn(__fadd_rn(l[sub], g), 0.9f);
        if (sub == 0 || s > sv) { sv = s; si = sub * 64 + c; }
      }
      argmax64(sv, si);
      // soft: scores, row max, exp (CR f32)
      float ssv[4];
#pragma unroll
      for (int sub = 0; sub < 4; ++sub) {
        float g = gumbel32(ks0, ks1, jb + (uint32_t)(sub * 64 + c));
        ssv[sub] = __fdiv_rn(__fadd_rn(l[sub], g), 0.9f);
      }
      float m = fmaxf(fmaxf(ssv[0], ssv[1]), fmaxf(ssv[2], ssv[3]));
#pragma unroll
      for (int off = 32; off >= 1; off >>= 1) m = fmaxf(m, __shfl_xor(m, off));
#pragma unroll
      for (int sub = 0; sub < 4; ++sub)
        sh[r * LGS + sub * 64 + c] = exp32cr(__fsub_rn(ssv[sub], m));
      if (c == 0) { selL[r] = si; idxL[r] = bi; }
    }
  }
  __syncthreads();

  // ph2b: numpy-pairwise softmax denom; 8 threads per row (32 rows).
  // Exact order: per half, acc_j = a[j]+a[8+j]+...+a[120+j] (15 seq adds), then
  // commutative-only shfl_xor(1,2,4) tree = ((r0+r1)+(r2+r3))+((r4+r5)+(r6+r7));
  // S = fadd(half0, half1) in ref order.  (R5/R6-verified)
  {
    const int r = t >> 3;        // 0..31
    const int j = t & 7;
    const float* a = sh + r * LGS;
    float acc0 = a[j];
#pragma unroll
    for (int i = 1; i < 16; ++i) acc0 = __fadd_rn(acc0, a[j + 8 * i]);
    float s0 = __fadd_rn(acc0, __shfl_xor(acc0, 1));
    s0 = __fadd_rn(s0, __shfl_xor(s0, 2));
    s0 = __fadd_rn(s0, __shfl_xor(s0, 4));
    float acc1 = a[128 + j];
#pragma unroll
    for (int i = 1; i < 16; ++i) acc1 = __fadd_rn(acc1, a[128 + j + 8 * i]);
    float s1 = __fadd_rn(acc1, __shfl_xor(acc1, 1));
    s1 = __fadd_rn(s1, __shfl_xor(s1, 2));
    s1 = __fadd_rn(s1, __shfl_xor(s1, 4));
    float S = __fadd_rn(s0, s1);
    if (j == 0) {
      const int n = n0 + r;
      int sel = selL[r];
      float wsv = __fdiv_rn(sh[r * LGS + sel], S);
      wsL[r] = __fadd_rn(__fsub_rn(1.0f, wsv), wsv);
      out[(size_t)NROWS * DIM + (size_t)n * 4 + stage] = (float)idxL[r];
    }
  }
  __syncthreads();

  // ph3/ph4 in column halves: p = fl32(wstar * C[sel][col]) (4 cols/lane/half),
  // out_sum RMW (per-col, ref order), p-half staged in sh (overlays dead exp buf),
  // ph4 broadcasts p via uniform ds_read; a2 accumulates d = 0..511 ascending.
  float a2[RPW][8];
  if (stage < 3) {
#pragma unroll
    for (int r = 0; r < RPW; ++r)
#pragma unroll
      for (int c = 0; c < 8; ++c) a2[r][c] = 0.0f;
  }
#pragma unroll 1
  for (int h = 0; h < 2; ++h) {
    float4 p4[RPW];
#pragma unroll
    for (int r = 0; r < RPW; ++r) {
      const int n = n0 + rb + r;
      const int sel = selL[rb + r];
      const float wv = wsL[rb + r];
      float4 cv = *(const float4*)(Cbi + (size_t)sel * 512 + h * 256 + 4 * L);
      p4[r].x = __fmul_rn(wv, cv.x); p4[r].y = __fmul_rn(wv, cv.y);
      p4[r].z = __fmul_rn(wv, cv.z); p4[r].w = __fmul_rn(wv, cv.w);
      float* orow = out + (size_t)n * 512 + h * 256 + 4 * L;
      if (stage == 0) {
        *(float4*)orow = p4[r];
      } else {
        float4 o = *(const float4*)orow;
        o.x = __fadd_rn(o.x, p4[r].x); o.y = __fadd_rn(o.y, p4[r].y);
        o.z = __fadd_rn(o.z, p4[r].z); o.w = __fadd_rn(o.w, p4[r].w);
        *(float4*)orow = o;
      }
    }
    if (stage < 3) {
      __syncthreads();   // exp buf (h=0) / prev p-half (h=1) fully consumed
#pragma unroll
      for (int r = 0; r < RPW; ++r)
        *(float4*)&sh[(rb + r) * LGS + 4 * L] = p4[r];
      __syncthreads();
      for (int dl = 0; dl < 256; dl += 2) {
        const int d = h * 256 + dl;
        const float* wr0 = Wr + (size_t)d * 512 + L * 8;
        float4 w00 = *(const float4*)wr0;
        float4 w01 = *(const float4*)(wr0 + 4);
        float4 w10 = *(const float4*)(wr0 + 512);
        float4 w11 = *(const float4*)(wr0 + 516);
        float wv0[8] = {w00.x, w00.y, w00.z, w00.w, w01.x, w01.y, w01.z, w01.w};
        float wv1[8] = {w10.x, w10.y, w10.z, w10.w, w11.x, w11.y, w11.z, w11.w};
        float2 ps[RPW];
#pragma unroll
        for (int r = 0; r < RPW; ++r)
          ps[r] = *(const float2*)&sh[(rb + r) * LGS + dl];   // uniform: broadcast
#pragma unroll
        for (int r = 0; r < RPW; ++r) {
#pragma unroll
          for (int c = 0; c < 8; ++c) a2[r][c] = fmaf(ps[r].x, wv0[c], a2[r][c]);
#pragma unroll
          for (int c = 0; c < 8; ++c) a2[r][c] = fmaf(ps[r].y, wv1[c], a2[r][c]);
        }
      }
    }
  }

  // x_next = x - p@Wr, write to global (own rows; in-place safe)
  if (stage < 3) {
#pragma unroll
    for (int r = 0; r < RPW; ++r) {
      const float* px = Xin + (size_t)(n0 + rb + r) * 512 + L * 8;
      float4 x0 = *(const float4*)px;
      float4 x1 = *(const float4*)(px + 4);
      float4 o0, o1;
      o0.x = __fsub_rn(x0.x, a2[r][0]); o0.y = __fsub_rn(x0.y, a2[r][1]);
      o0.z = __fsub_rn(x0.z, a2[r][2]); o0.w = __fsub_rn(x0.w, a2[r][3]);
      o1.x = __fsub_rn(x1.x, a2[r][4]); o1.y = __fsub_rn(x1.y, a2[r][5]);
      o1.z = __fsub_rn(x1.z, a2[r][6]); o1.w = __fsub_rn(x1.w, a2[r][7]);
      float* pxo = Xout + (size_t)(n0 + rb + r) * 512 + L * 8;
      *(float4*)pxo = o0;
      *(float4*)(pxo + 4) = o1;
    }
  }
}

extern "C" void kernel_launch(void* const* d_in, const int* in_sizes, int n_in,
                              void* d_out, int out_size, void* d_ws, size_t ws_size,
                              hipStream_t stream) {
  const float* x  = (const float*)d_in[0];   // [65536,512]
  const float* Cb = (const float*)d_in[1];   // [4,256,512]
  const float* A  = (const float*)d_in[2];   // [4,512,512]
  const float* Wr = (const float*)d_in[3];   // [512,512]
  float* out = (float*)d_out;
  float* ws  = (float*)d_ws;

  float* cpd  = ws;                          // 4*512*256 = 524288 f (2 MB)
  float* xcur = ws + 524288;                 // 65536*512 f (134 MB)

  // keys: fold_in(key(42), i) -> split -> (k_soft = keys[0], k_hard = keys[1])
  uint32_t kh[4][2], ks[4][2];
  for (uint32_t i = 0; i < 4; ++i) {
    uint32_t f0, f1, a0, a1, b0, b1;
    tf2x32(0u, 42u, 0u, i, f0, f1);
    tf2x32(f0, f1, 0u, 0u, a0, a1);   // keys[0] -> k_soft
    tf2x32(f0, f1, 0u, 1u, b0, b1);   // keys[1] -> k_hard
    ks[i][0] = a0; ks[i][1] = a1;
    kh[i][0] = b0; kh[i][1] = b1;
  }

  k_cproj<<<dim3(256), dim3(256), 0, stream>>>(Cb, A, cpd);

  const int NB = NROWS / RPB;  // 2048
  for (int i = 0; i < 4; ++i) {
    const float* Xi = (i == 0) ? x : xcur;
    k_stage<<<dim3(NB), dim3(THR), 0, stream>>>(
        Xi, xcur, A + (size_t)i * DIM * DIM, cpd + (size_t)i * DIM * KCB,
        Cb + (size_t)i * KCB * DIM, Wr, out,
        kh[i][0], kh[i][1], ks[i][0], ks[i][1], i);
  }
}